// Round 6
// baseline (100.129 us; speedup 1.0000x reference)
//
#include <hip/hip_runtime.h>

#define TILE 32
#define HALO 2
#define LH (TILE + HALO)        // 34 rows: tile + bottom halo (no top halo needed)
#define LW (TILE + 2 * HALO)    // 36 cols
#define HT 512
#define WD 512

constexpr float W_IN  = 1.0f / 9.0f + 0.02f;   // 3x3 ring: 1/9 + 0.5/25
constexpr float W_OUT = 0.02f;                 // 5x5 outer ring: 0.5/25
constexpr float LN15C = 0.40546611f;           // ln(1.5) + eps(1e-6) folded in
// OOB cells staged as zeros -> pair d with deg-3 polys = 1.69383799
constexpr float INV_D_OOB = 0.59037527f;

struct Frac { float n, d; };
__device__ __forceinline__ Frac fmerge(Frac a, Frac b) {
    Frac r;
    r.n = __builtin_fmaf(a.n, b.d, b.n * a.d);
    r.d = a.d * b.d;
    return r;
}

// One unordered-pair fraction: n = w*(bce_a+bce_b), d = mutual + pairwise + eps.
// 18 VALU ops incl. 1 v_exp. Works for self-pair (ca==cb, pass w/2) and for
// OOB cb (= zeros): d == 1.69383799, n == w*bce_a (fixed up in edge blocks).
__device__ __forceinline__ Frac pairf(const float4 ca, const float4 cb, float w) {
    const float j = ca.x * cb.x;
    const float u = __expf(-fabsf(j));                       // e^{-|j|}
    const float t = __builtin_fmaf(u, 0.66666667f, -0.33333333f);
    float L = __builtin_fmaf(0.33333333f, t, -0.5f);         // ln(1+u), deg-3
    L = __builtin_fmaf(L, t, 1.0f);
    L = __builtin_fmaf(L, t, LN15C);
    const float m = __builtin_fmaf(-j, ca.y * cb.y, fmaxf(j, 0.f)) + L;
    const float z = __builtin_fmaf(ca.z, cb.z, -0.5f);       // gg - 0.5
    float E = __builtin_fmaf(-0.16666667f, z, 0.5f);         // e^{-gg}, deg-3
    E = __builtin_fmaf(E, z, -1.0f);
    E = __builtin_fmaf(E, z, 1.0f);
    Frac r;
    r.d = __builtin_fmaf(E, 0.60653066f, m);
    r.n = (ca.w + cb.w) * w;
    return r;
}

__global__ __launch_bounds__(256) void scloss_main(
    const float* __restrict__ pred, const float* __restrict__ target,
    float* __restrict__ out, double inv_cnt) {
    __shared__ float4 sh[LH * LW];   // (p, t, sigmoid(p), bce); OOB = zeros

    const int b = blockIdx.x >> 8;           // 256 tiles per image (512/32)^2
    const int tile = blockIdx.x & 255;
    const int ty0 = (tile >> 4) << 5;
    const int tx0 = (tile & 15) << 5;

    const float* pbase = pred + ((size_t)b << 18);
    const float* tbase = target + ((size_t)b << 18);
    const int tid = threadIdx.x;

    // Stage 34x36 cells; one exp serves sigmoid AND softplus. Div-free indices.
    int cy = tid / LW;
    int cx = tid - cy * LW;
    #pragma unroll
    for (int i = 0; i < 5; ++i) {
        const int idx = tid + (i << 8);
        if (idx < LH * LW) {
            const int gy = ty0 + cy;
            const int gx = tx0 + cx - HALO;
            float p = 0.f, t = 0.f, g = 0.f, bce = 0.f;
            if ((unsigned)gx < (unsigned)WD && gy < HT) {
                const int gi = (gy << 9) + gx;
                p = pbase[gi];
                t = tbase[gi];
                const float en = __expf(-fabsf(p));
                const float inv = __builtin_amdgcn_rcpf(1.f + en);
                g = (p >= 0.f) ? inv : en * inv;             // sigmoid(p)
                const float tt = __builtin_fmaf(en, 0.66666667f, -0.33333333f);
                float L = __builtin_fmaf(0.33333333f, tt, -0.5f);
                L = __builtin_fmaf(L, tt, 1.0f);
                L = __builtin_fmaf(L, tt, 0.40546511f);
                bce = __builtin_fmaf(-p, t, fmaxf(p, 0.f)) + L;
            }
            sh[idx] = make_float4(p, t, g, bce);
        }
        cx += 4; cy += 7;                    // 256 = 7*36 + 4
        if (cx >= LW) { cx -= LW; ++cy; }
    }
    __syncthreads();

    const int px = tid & 31;
    const int py0 = tid >> 5;
    float acc = 0.f;

    const bool edge = (tx0 == 0) | (tx0 == WD - TILE) | (ty0 == 0) | (ty0 == HT - TILE);

    constexpr int pdy[12] = {0, 0, 1, 1, 1, 1, 1, 2, 2, 2, 2, 2};
    constexpr int pdx[12] = {1, 2, -2, -1, 0, 1, 2, -2, -1, 0, 1, 2};
    constexpr float pw12[12] = {W_IN, W_OUT, W_OUT, W_IN, W_IN, W_IN,
                                W_OUT, W_OUT, W_OUT, W_OUT, W_OUT, W_OUT};

    #pragma unroll
    for (int r = 0; r < 4; ++r) {
        const int ay = py0 + (r << 3);
        const float4* base = &sh[ay * LW + px + HALO];
        const float4 ca = base[0];

        const Frac f0 = pairf(ca, ca, W_IN * 0.5f);          // self
        const Frac f1 = pairf(ca, base[1],          W_IN);
        const Frac f2 = pairf(ca, base[2],          W_OUT);
        const Frac f3 = pairf(ca, base[LW - 2],     W_OUT);
        const Frac f4 = pairf(ca, base[LW - 1],     W_IN);
        const Frac f5 = pairf(ca, base[LW],         W_IN);
        const Frac f6 = pairf(ca, base[LW + 1],     W_IN);
        const Frac f7 = pairf(ca, base[LW + 2],     W_OUT);
        const Frac f8 = pairf(ca, base[2 * LW - 2], W_OUT);
        const Frac f9 = pairf(ca, base[2 * LW - 1], W_OUT);
        const Frac fA = pairf(ca, base[2 * LW],     W_OUT);
        const Frac fB = pairf(ca, base[2 * LW + 1], W_OUT);
        const Frac fC = pairf(ca, base[2 * LW + 2], W_OUT);

        // Balanced 13-leaf fraction tree -> ONE rcp per pixel-row.
        const Frac a0 = fmerge(f0, f1), a1 = fmerge(f2, f3), a2 = fmerge(f4, f5);
        const Frac a3 = fmerge(f6, f7), a4 = fmerge(f8, f9), a5 = fmerge(fA, fB);
        const Frac b0 = fmerge(a0, a1), b1 = fmerge(a2, a3), b2 = fmerge(a4, a5);
        const Frac c0 = fmerge(b0, b1), c1 = fmerge(b2, fC);
        const Frac d0 = fmerge(c0, c1);
        acc = __builtin_fmaf(d0.n, __builtin_amdgcn_rcpf(d0.d), acc);

        // Edge blocks only (block-uniform, 60/2048): closed-form corrections.
        if (edge) {
            const int gy = ty0 + ay, gx = tx0 + px;
            #pragma unroll
            for (int k = 0; k < 12; ++k) {
                if (gy + pdy[k] >= HT || gx + pdx[k] < 0 || gx + pdx[k] >= WD)
                    acc += pw12[k] * (1.f - ca.w * INV_D_OOB);
                if (gy - pdy[k] < 0 || gx - pdx[k] < 0 || gx - pdx[k] >= WD)
                    acc += pw12[k];
            }
        }
    }

    // Block reduction -> one float atomic per block (pre-scaled).
    #pragma unroll
    for (int off = 32; off > 0; off >>= 1)
        acc += __shfl_down(acc, off, 64);
    __shared__ double wsum[4];
    if ((tid & 63) == 0) wsum[tid >> 6] = (double)acc;
    __syncthreads();
    if (tid == 0) {
        const double s = wsum[0] + wsum[1] + wsum[2] + wsum[3];
        atomicAdd(out, (float)(s * inv_cnt));
    }
}

extern "C" void kernel_launch(void* const* d_in, const int* in_sizes, int n_in,
                              void* d_out, int out_size, void* d_ws, size_t ws_size,
                              hipStream_t stream) {
    const float* pred   = (const float*)d_in[0];
    const float* target = (const float*)d_in[1];
    float* out = (float*)d_out;

    const int B = in_sizes[0] / (HT * WD);
    const int nblocks = B * 256;             // 2048 for B=8

    hipMemsetAsync(out, 0, sizeof(float), stream);
    scloss_main<<<nblocks, 256, 0, stream>>>(pred, target, out,
                                             1.0 / ((double)B * HT * WD));
}

// Round 8
// 97.554 us; speedup vs baseline: 1.0264x; 1.0264x over previous
//
#include <hip/hip_runtime.h>

#define TILE 32
#define HALO 2
#define LH (TILE + HALO)        // 34 rows: tile + bottom halo
#define LW (TILE + 2 * HALO)    // 36 cols
#define HT 512
#define WD 512

typedef _Float16 h2 __attribute__((ext_vector_type(2)));

constexpr float W_IN  = 1.0f / 9.0f + 0.02f;   // 3x3 ring: 1/9 + 0.5/25
constexpr float W_OUT = 0.02f;                 // 5x5 outer ring
// OOB cells staged as zeros -> d = L(1) + E(0) = 0.695589 + 0.998280 = 1.693869
constexpr float INV_D_OOB = 0.590364f;

// ln(1+u), u in [0,1], deg-3 monomial (err <= 4.2e-3):
//   0.098765 u^3 - 0.370370 u^2 + 0.962963 u + 0.004231
// e^{-g}, g in [0,1], deg-3 monomial (err <= 1.7e-3), eps folded:
//  -0.101088 g^3 + 0.454898 g^2 - 0.985612 g + 0.998280

__device__ __forceinline__ h2 pk2(float a, float b) {
    return __builtin_bit_cast(h2, __builtin_amdgcn_cvt_pkrtz(a, b));  // v_cvt_pk_rtz_f16_f32
}
__device__ __forceinline__ h2 hsp(float x) {
    h2 r; r.x = (_Float16)x; r.y = (_Float16)x; return r;
}
__device__ __forceinline__ h2 mkh(float a, float b) {
    h2 r; r.x = (_Float16)a; r.y = (_Float16)b; return r;
}

struct FracH { h2 n, d; };

// Two unordered-pair fractions against common center, packed in half2 lanes.
__device__ __forceinline__ FracH pair2h(float cax, h2 cay, h2 caz, h2 caw,
                                        const float4 cb1, const float4 cb2, h2 wv) {
    const float j1 = cax * cb1.x, j2 = cax * cb2.x;
    const h2 J = pk2(j1, j2);
    const h2 U = pk2(__expf(-fabsf(j1)), __expf(-fabsf(j2)));   // hw v_exp_f32
    const h2 T = pk2(cb1.y, cb2.y);
    const h2 G = pk2(cb1.z, cb2.z);
    const h2 Wb = pk2(cb1.w, cb2.w);
    h2 L = __builtin_elementwise_fma(U, hsp(0.098765f), hsp(-0.370370f));
    L = __builtin_elementwise_fma(L, U, hsp(0.962963f));
    L = __builtin_elementwise_fma(L, U, hsp(0.004231f));
    const h2 LAB = T * cay;                                     // exact: t in {0,1}
    const h2 mx = __builtin_elementwise_max(J, hsp(0.f));
    h2 m = __builtin_elementwise_fma(-J, LAB, mx);              // exact cancel at lab=1
    m = m + L;
    const h2 GG = G * caz;
    h2 E = __builtin_elementwise_fma(GG, hsp(-0.101088f), hsp(0.454898f));
    E = __builtin_elementwise_fma(E, GG, hsp(-0.985612f));
    E = __builtin_elementwise_fma(E, GG, hsp(0.998280f));
    FracH r;
    r.d = m + E;
    r.n = (Wb + caw) * wv;
    return r;
}

__device__ __forceinline__ FracH mergeh(FracH a, FracH b) {
    FracH r;
    r.n = __builtin_elementwise_fma(a.n, b.d, a.d * b.n);
    r.d = a.d * b.d;
    return r;
}

__global__ __launch_bounds__(256) void scloss_main(
    const float* __restrict__ pred, const float* __restrict__ target,
    float* __restrict__ out, double inv_cnt) {
    __shared__ float4 sh[LH * LW];   // (p, t, sigmoid(p), bce); OOB = zeros

    const int b = blockIdx.x >> 8;
    const int tile = blockIdx.x & 255;
    const int ty0 = (tile >> 4) << 5;
    const int tx0 = (tile & 15) << 5;

    const float* pbase = pred + ((size_t)b << 18);
    const float* tbase = target + ((size_t)b << 18);
    const int tid = threadIdx.x;

    // Stage 34x36 cells; one exp serves sigmoid AND softplus (fp32).
    int cy = tid / LW;
    int cx = tid - cy * LW;
    #pragma unroll
    for (int i = 0; i < 5; ++i) {
        const int idx = tid + (i << 8);
        if (idx < LH * LW) {
            const int gy = ty0 + cy;
            const int gx = tx0 + cx - HALO;
            float p = 0.f, t = 0.f, g = 0.f, bce = 0.f;
            if ((unsigned)gx < (unsigned)WD && gy < HT) {
                const int gi = (gy << 9) + gx;
                p = pbase[gi];
                t = tbase[gi];
                const float en = __expf(-fabsf(p));
                const float inv = __builtin_amdgcn_rcpf(1.f + en);
                g = (p >= 0.f) ? inv : en * inv;             // sigmoid(p)
                float L = fmaf(fmaf(fmaf(0.098765f, en, -0.370370f), en,
                                    0.962963f), en, 0.004231f);
                bce = fmaf(-p, t, fmaxf(p, 0.f)) + L;
            }
            sh[idx] = make_float4(p, t, g, bce);
        }
        cx += 4; cy += 7;                    // 256 = 7*36 + 4
        if (cx >= LW) { cx -= LW; ++cy; }
    }
    __syncthreads();

    const int px = tid & 31;
    const int py0 = tid >> 5;
    float acc = 0.f;

    const bool edge = (tx0 == 0) | (tx0 == WD - TILE) | (ty0 == 0) | (ty0 == HT - TILE);

    constexpr int pdy[12] = {0, 0, 1, 1, 1, 1, 1, 2, 2, 2, 2, 2};
    constexpr int pdx[12] = {1, 2, -2, -1, 0, 1, 2, -2, -1, 0, 1, 2};
    constexpr float pw12[12] = {W_IN, W_OUT, W_OUT, W_IN, W_IN, W_IN,
                                W_OUT, W_OUT, W_OUT, W_OUT, W_OUT, W_OUT};

    #pragma unroll
    for (int r = 0; r < 4; ++r) {
        const int ay = py0 + (r << 3);
        const float4* base = &sh[ay * LW + px + HALO];
        const float4 ca = base[0];

        // center splats for the packed domain
        const h2 cay = hsp(ca.y), caz = pk2(ca.z, ca.z), caw = pk2(ca.w, ca.w);

        // self pair, fp32 scalar (j0 >= 0)
        const float j0 = ca.x * ca.x;
        const float u0 = __expf(-j0);
        const float L0 = fmaf(fmaf(fmaf(0.098765f, u0, -0.370370f), u0,
                                   0.962963f), u0, 0.004231f);
        const float m0 = fmaf(-j0, ca.y * ca.y, j0) + L0;
        const float gg0 = ca.z * ca.z;
        const float E0 = fmaf(fmaf(fmaf(-0.101088f, gg0, 0.454898f), gg0,
                                   -0.985612f), gg0, 0.998280f);
        const float d0 = m0 + E0;
        const float n0 = W_IN * ca.w;

        // 6 packed groups = 12 half-plane pairs
        const FracH F1 = pair2h(ca.x, cay, caz, caw, base[1],          base[2],          mkh(W_IN,  W_OUT));
        const FracH F2 = pair2h(ca.x, cay, caz, caw, base[LW - 2],     base[LW - 1],     mkh(W_OUT, W_IN));
        const FracH F3 = pair2h(ca.x, cay, caz, caw, base[LW],         base[LW + 1],     mkh(W_IN,  W_IN));
        const FracH F4 = pair2h(ca.x, cay, caz, caw, base[LW + 2],     base[2 * LW - 2], mkh(W_OUT, W_OUT));
        const FracH F5 = pair2h(ca.x, cay, caz, caw, base[2 * LW - 1], base[2 * LW],     mkh(W_OUT, W_OUT));
        const FracH F6 = pair2h(ca.x, cay, caz, caw, base[2 * LW + 1], base[2 * LW + 2], mkh(W_OUT, W_OUT));

        // Packed fraction tree (5 packed merges), then fp32 finish.
        const FracH A = mergeh(F1, F2);
        const FracH Bb = mergeh(F3, F4);
        const FracH C = mergeh(F5, F6);
        const FracH D2 = mergeh(A, Bb);
        const FracH G2 = mergeh(D2, C);

        const float nl = (float)G2.n.x, nh = (float)G2.n.y;
        const float dl = (float)G2.d.x, dh = (float)G2.d.y;
        const float Nt = fmaf(nl, dh, nh * dl), Dt = dl * dh;
        const float Nf = fmaf(n0, Dt, Nt * d0), Df = d0 * Dt;
        acc = fmaf(Nf, __builtin_amdgcn_rcpf(Df), acc);

        // Edge blocks only (block-uniform, 60/2048): closed-form corrections.
        if (edge) {
            const int gy = ty0 + ay, gx = tx0 + px;
            #pragma unroll
            for (int k = 0; k < 12; ++k) {
                if (gy + pdy[k] >= HT || gx + pdx[k] < 0 || gx + pdx[k] >= WD)
                    acc += pw12[k] * (1.f - ca.w * INV_D_OOB);
                if (gy - pdy[k] < 0 || gx - pdx[k] < 0 || gx - pdx[k] >= WD)
                    acc += pw12[k];
            }
        }
    }

    // Block reduction -> one float atomic per block (pre-scaled).
    #pragma unroll
    for (int off = 32; off > 0; off >>= 1)
        acc += __shfl_down(acc, off, 64);
    __shared__ double wsum[4];
    if ((tid & 63) == 0) wsum[tid >> 6] = (double)acc;
    __syncthreads();
    if (tid == 0) {
        const double s = wsum[0] + wsum[1] + wsum[2] + wsum[3];
        atomicAdd(out, (float)(s * inv_cnt));
    }
}

extern "C" void kernel_launch(void* const* d_in, const int* in_sizes, int n_in,
                              void* d_out, int out_size, void* d_ws, size_t ws_size,
                              hipStream_t stream) {
    const float* pred   = (const float*)d_in[0];
    const float* target = (const float*)d_in[1];
    float* out = (float*)d_out;

    const int B = in_sizes[0] / (HT * WD);
    const int nblocks = B * 256;

    (void)hipMemsetAsync(out, 0, sizeof(float), stream);
    scloss_main<<<nblocks, 256, 0, stream>>>(pred, target, out,
                                             1.0 / ((double)B * HT * WD));
}

// Round 9
// 97.540 us; speedup vs baseline: 1.0265x; 1.0001x over previous
//
#include <hip/hip_runtime.h>

#define TILE 32
#define HALO 2
#define LH (TILE + HALO)        // 34 rows: tile + bottom halo
#define LW (TILE + 2 * HALO)    // 36 cols
#define HT 512
#define WD 512

typedef _Float16 h2 __attribute__((ext_vector_type(2)));

constexpr float W_IN  = 1.0f / 9.0f + 0.02f;   // 3x3 ring: 1/9 + 0.5/25
constexpr float W_OUT = 0.02f;                 // 5x5 outer ring
// OOB cells staged as zeros -> d = L(1) + E(0) = 0.695589 + 0.998280 = 1.693869
constexpr float INV_D_OOB = 0.590364f;

// ln(1+u), u in [0,1], deg-3 monomial (err <= 4.2e-3):
//   0.098765 u^3 - 0.370370 u^2 + 0.962963 u + 0.004231
// e^{-g}, g in [0,1], deg-3 monomial (err <= 1.7e-3), eps folded:
//  -0.101088 g^3 + 0.454898 g^2 - 0.985612 g + 0.998280

__device__ __forceinline__ h2 pk2(float a, float b) {
    return __builtin_bit_cast(h2, __builtin_amdgcn_cvt_pkrtz(a, b));  // v_cvt_pk_rtz_f16_f32
}
__device__ __forceinline__ h2 hsp(float x) {
    h2 r; r.x = (_Float16)x; r.y = (_Float16)x; return r;
}
__device__ __forceinline__ h2 mkh(float a, float b) {
    h2 r; r.x = (_Float16)a; r.y = (_Float16)b; return r;
}

struct FracH { h2 n, d; };

// Two unordered-pair fractions against common center, packed in half2 lanes.
__device__ __forceinline__ FracH pair2h(float cax, h2 cay, h2 caz, h2 caw,
                                        const float4 cb1, const float4 cb2, h2 wv) {
    const float j1 = cax * cb1.x, j2 = cax * cb2.x;
    const h2 J = pk2(j1, j2);
    const h2 U = pk2(__expf(-fabsf(j1)), __expf(-fabsf(j2)));   // hw v_exp_f32
    const h2 T = pk2(cb1.y, cb2.y);
    const h2 G = pk2(cb1.z, cb2.z);
    const h2 Wb = pk2(cb1.w, cb2.w);
    h2 L = __builtin_elementwise_fma(U, hsp(0.098765f), hsp(-0.370370f));
    L = __builtin_elementwise_fma(L, U, hsp(0.962963f));
    L = __builtin_elementwise_fma(L, U, hsp(0.004231f));
    const h2 LAB = T * cay;                                     // exact: t in {0,1}
    const h2 mx = __builtin_elementwise_max(J, hsp(0.f));
    h2 m = __builtin_elementwise_fma(-J, LAB, mx);              // exact cancel at lab=1
    m = m + L;
    const h2 GG = G * caz;
    h2 E = __builtin_elementwise_fma(GG, hsp(-0.101088f), hsp(0.454898f));
    E = __builtin_elementwise_fma(E, GG, hsp(-0.985612f));
    E = __builtin_elementwise_fma(E, GG, hsp(0.998280f));
    FracH r;
    r.d = m + E;
    r.n = (Wb + caw) * wv;
    return r;
}

__device__ __forceinline__ FracH mergeh(FracH a, FracH b) {
    FracH r;
    r.n = __builtin_elementwise_fma(a.n, b.d, a.d * b.n);
    r.d = a.d * b.d;
    return r;
}

// (256, 4): min 4 waves/EU -> VGPR cap 128. LDS (19.5 KB) limits residency to
// 8 blocks/CU anyway; trade occupancy for register room so the 13-pair tree
// stays live instead of being re-materialized at VGPR=32.
__global__ __launch_bounds__(256, 4) void scloss_main(
    const float* __restrict__ pred, const float* __restrict__ target,
    float* __restrict__ out, double inv_cnt) {
    __shared__ float4 sh[LH * LW];   // (p, t, sigmoid(p), bce); OOB = zeros

    const int b = blockIdx.x >> 8;
    const int tile = blockIdx.x & 255;
    const int ty0 = (tile >> 4) << 5;
    const int tx0 = (tile & 15) << 5;

    const float* pbase = pred + ((size_t)b << 18);
    const float* tbase = target + ((size_t)b << 18);
    const int tid = threadIdx.x;

    // Stage 34x36 cells; one exp serves sigmoid AND softplus (fp32).
    int cy = tid / LW;
    int cx = tid - cy * LW;
    #pragma unroll
    for (int i = 0; i < 5; ++i) {
        const int idx = tid + (i << 8);
        if (idx < LH * LW) {
            const int gy = ty0 + cy;
            const int gx = tx0 + cx - HALO;
            float p = 0.f, t = 0.f, g = 0.f, bce = 0.f;
            if ((unsigned)gx < (unsigned)WD && gy < HT) {
                const int gi = (gy << 9) + gx;
                p = pbase[gi];
                t = tbase[gi];
                const float en = __expf(-fabsf(p));
                const float inv = __builtin_amdgcn_rcpf(1.f + en);
                g = (p >= 0.f) ? inv : en * inv;             // sigmoid(p)
                float L = fmaf(fmaf(fmaf(0.098765f, en, -0.370370f), en,
                                    0.962963f), en, 0.004231f);
                bce = fmaf(-p, t, fmaxf(p, 0.f)) + L;
            }
            sh[idx] = make_float4(p, t, g, bce);
        }
        cx += 4; cy += 7;                    // 256 = 7*36 + 4
        if (cx >= LW) { cx -= LW; ++cy; }
    }
    __syncthreads();

    const int px = tid & 31;
    const int py0 = tid >> 5;
    float acc = 0.f;

    const bool edge = (tx0 == 0) | (tx0 == WD - TILE) | (ty0 == 0) | (ty0 == HT - TILE);

    constexpr int pdy[12] = {0, 0, 1, 1, 1, 1, 1, 2, 2, 2, 2, 2};
    constexpr int pdx[12] = {1, 2, -2, -1, 0, 1, 2, -2, -1, 0, 1, 2};
    constexpr float pw12[12] = {W_IN, W_OUT, W_OUT, W_IN, W_IN, W_IN,
                                W_OUT, W_OUT, W_OUT, W_OUT, W_OUT, W_OUT};

    #pragma unroll
    for (int r = 0; r < 4; ++r) {
        const int ay = py0 + (r << 3);
        const float4* base = &sh[ay * LW + px + HALO];
        const float4 ca = base[0];

        // center splats for the packed domain
        const h2 cay = hsp(ca.y), caz = pk2(ca.z, ca.z), caw = pk2(ca.w, ca.w);

        // self pair, fp32 scalar (j0 >= 0)
        const float j0 = ca.x * ca.x;
        const float u0 = __expf(-j0);
        const float L0 = fmaf(fmaf(fmaf(0.098765f, u0, -0.370370f), u0,
                                   0.962963f), u0, 0.004231f);
        const float m0 = fmaf(-j0, ca.y * ca.y, j0) + L0;
        const float gg0 = ca.z * ca.z;
        const float E0 = fmaf(fmaf(fmaf(-0.101088f, gg0, 0.454898f), gg0,
                                   -0.985612f), gg0, 0.998280f);
        const float d0 = m0 + E0;
        const float n0 = W_IN * ca.w;

        // 6 packed groups = 12 half-plane pairs
        const FracH F1 = pair2h(ca.x, cay, caz, caw, base[1],          base[2],          mkh(W_IN,  W_OUT));
        const FracH F2 = pair2h(ca.x, cay, caz, caw, base[LW - 2],     base[LW - 1],     mkh(W_OUT, W_IN));
        const FracH F3 = pair2h(ca.x, cay, caz, caw, base[LW],         base[LW + 1],     mkh(W_IN,  W_IN));
        const FracH F4 = pair2h(ca.x, cay, caz, caw, base[LW + 2],     base[2 * LW - 2], mkh(W_OUT, W_OUT));
        const FracH F5 = pair2h(ca.x, cay, caz, caw, base[2 * LW - 1], base[2 * LW],     mkh(W_OUT, W_OUT));
        const FracH F6 = pair2h(ca.x, cay, caz, caw, base[2 * LW + 1], base[2 * LW + 2], mkh(W_OUT, W_OUT));

        // Packed fraction tree (5 packed merges), then fp32 finish.
        const FracH A = mergeh(F1, F2);
        const FracH Bb = mergeh(F3, F4);
        const FracH C = mergeh(F5, F6);
        const FracH D2 = mergeh(A, Bb);
        const FracH G2 = mergeh(D2, C);

        const float nl = (float)G2.n.x, nh = (float)G2.n.y;
        const float dl = (float)G2.d.x, dh = (float)G2.d.y;
        const float Nt = fmaf(nl, dh, nh * dl), Dt = dl * dh;
        const float Nf = fmaf(n0, Dt, Nt * d0), Df = d0 * Dt;
        acc = fmaf(Nf, __builtin_amdgcn_rcpf(Df), acc);

        // Edge blocks only (block-uniform, 60/2048): closed-form corrections.
        if (edge) {
            const int gy = ty0 + ay, gx = tx0 + px;
            #pragma unroll
            for (int k = 0; k < 12; ++k) {
                if (gy + pdy[k] >= HT || gx + pdx[k] < 0 || gx + pdx[k] >= WD)
                    acc += pw12[k] * (1.f - ca.w * INV_D_OOB);
                if (gy - pdy[k] < 0 || gx - pdx[k] < 0 || gx - pdx[k] >= WD)
                    acc += pw12[k];
            }
        }
    }

    // Block reduction -> one float atomic per block (pre-scaled).
    #pragma unroll
    for (int off = 32; off > 0; off >>= 1)
        acc += __shfl_down(acc, off, 64);
    __shared__ double wsum[4];
    if ((tid & 63) == 0) wsum[tid >> 6] = (double)acc;
    __syncthreads();
    if (tid == 0) {
        const double s = wsum[0] + wsum[1] + wsum[2] + wsum[3];
        atomicAdd(out, (float)(s * inv_cnt));
    }
}

extern "C" void kernel_launch(void* const* d_in, const int* in_sizes, int n_in,
                              void* d_out, int out_size, void* d_ws, size_t ws_size,
                              hipStream_t stream) {
    const float* pred   = (const float*)d_in[0];
    const float* target = (const float*)d_in[1];
    float* out = (float*)d_out;

    const int B = in_sizes[0] / (HT * WD);
    const int nblocks = B * 256;

    (void)hipMemsetAsync(out, 0, sizeof(float), stream);
    scloss_main<<<nblocks, 256, 0, stream>>>(pred, target, out,
                                             1.0 / ((double)B * HT * WD));
}

// Round 10
// 92.038 us; speedup vs baseline: 1.0879x; 1.0598x over previous
//
#include <hip/hip_runtime.h>

#define TILE 16
#define HALO 2
#define LH (TILE + HALO)        // 18 rows: tile + bottom halo (no top halo needed)
#define LW (TILE + 2 * HALO)    // 20 cols
#define HT 512
#define WD 512

typedef _Float16 h2 __attribute__((ext_vector_type(2)));

constexpr float W_IN  = 1.0f / 9.0f + 0.02f;   // 3x3 ring: 1/9 + 0.5/25
constexpr float W_OUT = 0.02f;                 // 5x5 outer ring
// OOB cells staged as zeros -> d = L(1) + E(0) = 1.693869
constexpr float INV_D_OOB = 0.590364f;

// ln(1+u), u in [0,1], deg-3 monomial (err <= 4.2e-3)
// e^{-g}, g in [0,1], deg-3 monomial (err <= 1.7e-3), eps folded

__device__ __forceinline__ h2 pk2(float a, float b) {
    return __builtin_bit_cast(h2, __builtin_amdgcn_cvt_pkrtz(a, b));
}
__device__ __forceinline__ h2 hsp(float x) {
    h2 r; r.x = (_Float16)x; r.y = (_Float16)x; return r;
}
__device__ __forceinline__ h2 mkh(float a, float b) {
    h2 r; r.x = (_Float16)a; r.y = (_Float16)b; return r;
}

struct FracH { h2 n, d; };

__device__ __forceinline__ FracH pair2h(float cax, h2 cay, h2 caz, h2 caw,
                                        const float4 cb1, const float4 cb2, h2 wv) {
    const float j1 = cax * cb1.x, j2 = cax * cb2.x;
    const h2 J = pk2(j1, j2);
    const h2 U = pk2(__expf(-fabsf(j1)), __expf(-fabsf(j2)));
    const h2 T = pk2(cb1.y, cb2.y);
    const h2 G = pk2(cb1.z, cb2.z);
    const h2 Wb = pk2(cb1.w, cb2.w);
    h2 L = __builtin_elementwise_fma(U, hsp(0.098765f), hsp(-0.370370f));
    L = __builtin_elementwise_fma(L, U, hsp(0.962963f));
    L = __builtin_elementwise_fma(L, U, hsp(0.004231f));
    const h2 LAB = T * cay;
    const h2 mx = __builtin_elementwise_max(J, hsp(0.f));
    h2 m = __builtin_elementwise_fma(-J, LAB, mx);
    m = m + L;
    const h2 GG = G * caz;
    h2 E = __builtin_elementwise_fma(GG, hsp(-0.101088f), hsp(0.454898f));
    E = __builtin_elementwise_fma(E, GG, hsp(-0.985612f));
    E = __builtin_elementwise_fma(E, GG, hsp(0.998280f));
    FracH r;
    r.d = m + E;
    r.n = (Wb + caw) * wv;
    return r;
}

__device__ __forceinline__ FracH mergeh(FracH a, FracH b) {
    FracH r;
    r.n = __builtin_elementwise_fma(a.n, b.d, a.d * b.n);
    r.d = a.d * b.d;
    return r;
}

__global__ __launch_bounds__(256) void scloss_main(
    const float* __restrict__ pred, const float* __restrict__ target,
    double* __restrict__ partial) {
    __shared__ float4 sh[LH * LW];   // (p, t, sigmoid(p), bce); OOB = zeros

    const int b = blockIdx.x >> 10;          // 1024 tiles/image ((512/16)^2)
    const int tile = blockIdx.x & 1023;
    const int ty0 = (tile >> 5) << 4;
    const int tx0 = (tile & 31) << 4;

    const float* pbase = pred + ((size_t)b << 18);
    const float* tbase = target + ((size_t)b << 18);
    const int tid = threadIdx.x;

    // Stage 18x20 = 360 cells with 256 threads (2 passes).
    #pragma unroll
    for (int i = 0; i < 2; ++i) {
        const int idx = tid + (i << 8);
        if (idx < LH * LW) {
            const int cy = idx / LW;
            const int cx = idx - cy * LW;
            const int gy = ty0 + cy;
            const int gx = tx0 + cx - HALO;
            float p = 0.f, t = 0.f, g = 0.f, bce = 0.f;
            if ((unsigned)gx < (unsigned)WD && gy < HT) {
                const int gi = (gy << 9) + gx;
                p = pbase[gi];
                t = tbase[gi];
                const float en = __expf(-fabsf(p));
                const float inv = __builtin_amdgcn_rcpf(1.f + en);
                g = (p >= 0.f) ? inv : en * inv;             // sigmoid(p)
                float L = fmaf(fmaf(fmaf(0.098765f, en, -0.370370f), en,
                                    0.962963f), en, 0.004231f);
                bce = fmaf(-p, t, fmaxf(p, 0.f)) + L;
            }
            sh[idx] = make_float4(p, t, g, bce);
        }
    }
    __syncthreads();

    const int px = tid & 15;
    const int py = tid >> 4;                 // one pixel per thread
    float acc = 0.f;

    const bool edge = (tx0 == 0) | (tx0 == WD - TILE) | (ty0 == 0) | (ty0 == HT - TILE);

    constexpr int pdy[12] = {0, 0, 1, 1, 1, 1, 1, 2, 2, 2, 2, 2};
    constexpr int pdx[12] = {1, 2, -2, -1, 0, 1, 2, -2, -1, 0, 1, 2};
    constexpr float pw12[12] = {W_IN, W_OUT, W_OUT, W_IN, W_IN, W_IN,
                                W_OUT, W_OUT, W_OUT, W_OUT, W_OUT, W_OUT};

    {
        const float4* base = &sh[py * LW + px + HALO];
        const float4 ca = base[0];

        const h2 cay = hsp(ca.y), caz = pk2(ca.z, ca.z), caw = pk2(ca.w, ca.w);

        // self pair, fp32 scalar (j0 >= 0)
        const float j0 = ca.x * ca.x;
        const float u0 = __expf(-j0);
        const float L0 = fmaf(fmaf(fmaf(0.098765f, u0, -0.370370f), u0,
                                   0.962963f), u0, 0.004231f);
        const float m0 = fmaf(-j0, ca.y * ca.y, j0) + L0;
        const float gg0 = ca.z * ca.z;
        const float E0 = fmaf(fmaf(fmaf(-0.101088f, gg0, 0.454898f), gg0,
                                   -0.985612f), gg0, 0.998280f);
        const float d0 = m0 + E0;
        const float n0 = W_IN * ca.w;

        const FracH F1 = pair2h(ca.x, cay, caz, caw, base[1],          base[2],          mkh(W_IN,  W_OUT));
        const FracH F2 = pair2h(ca.x, cay, caz, caw, base[LW - 2],     base[LW - 1],     mkh(W_OUT, W_IN));
        const FracH F3 = pair2h(ca.x, cay, caz, caw, base[LW],         base[LW + 1],     mkh(W_IN,  W_IN));
        const FracH F4 = pair2h(ca.x, cay, caz, caw, base[LW + 2],     base[2 * LW - 2], mkh(W_OUT, W_OUT));
        const FracH F5 = pair2h(ca.x, cay, caz, caw, base[2 * LW - 1], base[2 * LW],     mkh(W_OUT, W_OUT));
        const FracH F6 = pair2h(ca.x, cay, caz, caw, base[2 * LW + 1], base[2 * LW + 2], mkh(W_OUT, W_OUT));

        const FracH A = mergeh(F1, F2);
        const FracH Bb = mergeh(F3, F4);
        const FracH C = mergeh(F5, F6);
        const FracH D2 = mergeh(A, Bb);
        const FracH G2 = mergeh(D2, C);

        const float nl = (float)G2.n.x, nh = (float)G2.n.y;
        const float dl = (float)G2.d.x, dh = (float)G2.d.y;
        const float Nt = fmaf(nl, dh, nh * dl), Dt = dl * dh;
        const float Nf = fmaf(n0, Dt, Nt * d0), Df = d0 * Dt;
        acc = fmaf(Nf, __builtin_amdgcn_rcpf(Df), acc);

        if (edge) {
            const int gy = ty0 + py, gx = tx0 + px;
            #pragma unroll
            for (int k = 0; k < 12; ++k) {
                if (gy + pdy[k] >= HT || gx + pdx[k] < 0 || gx + pdx[k] >= WD)
                    acc += pw12[k] * (1.f - ca.w * INV_D_OOB);
                if (gy - pdy[k] < 0 || gx - pdx[k] < 0 || gx - pdx[k] >= WD)
                    acc += pw12[k];
            }
        }
    }

    // Block reduction -> per-block partial (raw sum, double).
    #pragma unroll
    for (int off = 32; off > 0; off >>= 1)
        acc += __shfl_down(acc, off, 64);
    __shared__ double wsum[4];
    if ((tid & 63) == 0) wsum[tid >> 6] = (double)acc;
    __syncthreads();
    if (tid == 0)
        partial[blockIdx.x] = wsum[0] + wsum[1] + wsum[2] + wsum[3];
}

__global__ __launch_bounds__(256) void scloss_reduce(
    const double* __restrict__ partial, int n, float* __restrict__ out,
    double inv_cnt) {
    __shared__ double sm[256];
    double s = 0.0;
    for (int i = threadIdx.x; i < n; i += 256) s += partial[i];
    sm[threadIdx.x] = s;
    __syncthreads();
    for (int off = 128; off > 0; off >>= 1) {
        if (threadIdx.x < off) sm[threadIdx.x] += sm[threadIdx.x + off];
        __syncthreads();
    }
    if (threadIdx.x == 0) out[0] = (float)(sm[0] * inv_cnt);
}

extern "C" void kernel_launch(void* const* d_in, const int* in_sizes, int n_in,
                              void* d_out, int out_size, void* d_ws, size_t ws_size,
                              hipStream_t stream) {
    const float* pred   = (const float*)d_in[0];
    const float* target = (const float*)d_in[1];
    float* out = (float*)d_out;

    const int B = in_sizes[0] / (HT * WD);
    const int nblocks = B * 1024;            // 8192 for B=8

    double* partial = (double*)d_ws;
    scloss_main<<<nblocks, 256, 0, stream>>>(pred, target, partial);
    scloss_reduce<<<1, 256, 0, stream>>>(partial, nblocks, out,
                                         1.0 / ((double)B * HT * WD));
}